// Round 19
// baseline (229.648 us; speedup 1.0000x reference)
//
#include <hip/hip_runtime.h>
#include <hip/hip_fp16.h>
#include <math.h>

#define N_NODES 20000
#define N_EDGES 400000
#define BATCH   4096
#define MTILES  (N_NODES / 16)   // 1250
#define XSCALE  1024.0f
#define XINV    (1.0f / 1024.0f)

typedef __attribute__((ext_vector_type(8))) short short8v;
typedef __attribute__((ext_vector_type(4))) float f32x4;
typedef __attribute__((ext_vector_type(2))) _Float16 h2v;

// fp16 dot-pair with fp32 accumulate (v_dot2_f32_f16); fp32 fallback if absent
__device__ __forceinline__ float fdot2h(h2v a, h2v b, float c)
{
#if __has_builtin(__builtin_amdgcn_fdot2)
    return __builtin_amdgcn_fdot2(a, b, c, false);
#else
    return fmaf((float)a[0], (float)b[0], fmaf((float)a[1], (float)b[1], c));
#endif
}

__device__ __forceinline__ h2v mk_h2(float x, float y)
{
    h2v r; r[0] = (_Float16)x; r[1] = (_Float16)y; return r;
}

// ---- split fp32 into bf16 hi + bf16 lo (truncation; hi+lo ~ 16 mantissa bits)
__device__ __forceinline__ void bf16split(float v, short& h, short& l)
{
    unsigned u  = __float_as_uint(v);
    unsigned hu = u & 0xFFFF0000u;
    h = (short)(hu >> 16);
    const float lo = v - __uint_as_float(hu);
    l = (short)(__float_as_uint(lo) >> 16);
}

// ---- prep: zero deg (t < N_NODES) + pack ALL 4 layers' W into B-fragments
__global__ __launch_bounds__(256)
void prep_kernel(int* __restrict__ deg,
                 const float* __restrict__ Wl0, const float* __restrict__ Wr0,
                 const float* __restrict__ Wl1, const float* __restrict__ Wr1,
                 const float* __restrict__ Wl2, const float* __restrict__ Wr2,
                 const float* __restrict__ Wl3, const float* __restrict__ Wr3,
                 short* __restrict__ wpk)
{
    const int t = blockIdx.x * 256 + threadIdx.x;
    if (t < N_NODES) { deg[t] = 0; return; }
    const int tp = t - N_NODES;
    if (tp >= 14336) return;
    int layer, base, K;
    const float *Wl, *Wr;
    if (tp < 2048)       { layer = 0; base = 0;     K = 64;  Wl = Wl0; Wr = Wr0; }
    else if (tp < 6144)  { layer = 1; base = 2048;  K = 128; Wl = Wl1; Wr = Wr1; }
    else if (tp < 10240) { layer = 2; base = 6144;  K = 128; Wl = Wl2; Wr = Wr2; }
    else                 { layer = 3; base = 10240; K = 128; Wl = Wl3; Wr = Wr3; }
    const int KB   = K / 32;
    const int tt   = tp - base;
    const int lane = tt & 63;
    const int kb   = (tt >> 6) % KB;
    const int nt   = tt / (64 * KB);
    const float* W = (nt < 8) ? Wl : Wr;
    const int col  = (nt & 7) * 16 + (lane & 15);
    const int k0   = kb * 32 + (lane >> 4) * 8;
    short8v h, l;
#pragma unroll
    for (int e = 0; e < 8; ++e) {
        short hh, ll; bf16split(W[(size_t)(k0 + e) * 128 + col], hh, ll);
        h[e] = hh; l[e] = ll;
    }
    short* ob = wpk + (size_t)layer * 65536
                    + ((size_t)(nt * KB + kb) * 2) * 512 + lane * 8;
    *(short8v*)ob         = h;
    *(short8v*)(ob + 512) = l;
}

// ---- layer-0 MFMA transform: stages fp32 emb in LDS, splits to bf16 hi/lo.
// xl written as fp16 * XSCALE; xr stays fp32.
template<int KB, int NWAVES>
__global__ __launch_bounds__(NWAVES * 64)
void mfma_transform_kernel(const float* __restrict__ x,
                           const short* __restrict__ wpk,
                           __half* __restrict__ xlh, float* __restrict__ xr)
{
    constexpr int K  = KB * 32;
    constexpr int KP = K + 4;
    __shared__ float xs[16 * KP];
    const int mtile = blockIdx.x;
    const int wid   = threadIdx.x >> 6;
    const int lane  = threadIdx.x & 63;

    {
        const float4* __restrict__ src = (const float4*)(x + (size_t)mtile * 16 * K);
        for (int idx = threadIdx.x; idx < 16 * K / 4; idx += NWAVES * 64) {
            const int row = idx / (K / 4), c4 = idx % (K / 4);
            *(float4*)(xs + row * KP + c4 * 4) = src[idx];
        }
    }
    __syncthreads();

    short8v ah[KB], al[KB];
    {
        const float* ab = xs + (lane & 15) * KP + (lane >> 4) * 8;
#pragma unroll
        for (int kb = 0; kb < KB; ++kb) {
            const float4 f0 = *(const float4*)(ab + kb * 32);
            const float4 f1 = *(const float4*)(ab + kb * 32 + 4);
            float tmp[8] = {f0.x, f0.y, f0.z, f0.w, f1.x, f1.y, f1.z, f1.w};
#pragma unroll
            for (int e = 0; e < 8; ++e) {
                short hh, ll; bf16split(tmp[e], hh, ll);
                ah[kb][e] = hh; al[kb][e] = ll;
            }
        }
    }

#pragma unroll
    for (int i = 0; i < 4; ++i) {
        const int nt = wid * 4 + i;
        const short* bb = wpk + ((size_t)nt * KB * 2) * 512 + lane * 8;
        f32x4 acc = {0.f, 0.f, 0.f, 0.f};
#pragma unroll
        for (int kb = 0; kb < KB; ++kb) {
            const short8v bh = *(const short8v*)(bb + (size_t)(kb * 2 + 0) * 512);
            const short8v bl = *(const short8v*)(bb + (size_t)(kb * 2 + 1) * 512);
            acc = __builtin_amdgcn_mfma_f32_16x16x32_bf16(ah[kb], bh, acc, 0, 0, 0);
            acc = __builtin_amdgcn_mfma_f32_16x16x32_bf16(ah[kb], bl, acc, 0, 0, 0);
            acc = __builtin_amdgcn_mfma_f32_16x16x32_bf16(al[kb], bh, acc, 0, 0, 0);
        }
        const int colb = (nt & 7) * 16 + (lane & 15);
        const int row0 = mtile * 16 + (lane >> 4) * 4;
        if (nt < 8) {
#pragma unroll
            for (int r = 0; r < 4; ++r)
                xlh[(size_t)(row0 + r) * 128 + colb] = __float2half(acc[r] * XSCALE);
        } else {
#pragma unroll
            for (int r = 0; r < 4; ++r)
                xr[(size_t)(row0 + r) * 128 + colb] = acc[r];
        }
    }
}

// ---- layers 1,2 transform: consume pre-packed A-fragments (written by gat
// epilogue) -- no LDS stage, no split. K=128 fixed (KB=4). 16 N-tiles, 4 waves.
__global__ __launch_bounds__(256)
void mfma_transform_frag_kernel(const short* __restrict__ xfrag,
                                const short* __restrict__ wpk,
                                __half* __restrict__ xlh, float* __restrict__ xr)
{
    const int mtile = blockIdx.x;
    const int wid   = threadIdx.x >> 6;
    const int lane  = threadIdx.x & 63;

    short8v ah[4], al[4];
    const short* ab = xfrag + ((size_t)mtile * 4 * 2) * 512 + lane * 8;
#pragma unroll
    for (int kb = 0; kb < 4; ++kb) {
        ah[kb] = *(const short8v*)(ab + (size_t)(kb * 2 + 0) * 512);
        al[kb] = *(const short8v*)(ab + (size_t)(kb * 2 + 1) * 512);
    }

#pragma unroll
    for (int i = 0; i < 4; ++i) {
        const int nt = wid * 4 + i;
        const short* bb = wpk + ((size_t)nt * 4 * 2) * 512 + lane * 8;
        f32x4 acc = {0.f, 0.f, 0.f, 0.f};
#pragma unroll
        for (int kb = 0; kb < 4; ++kb) {
            const short8v bh = *(const short8v*)(bb + (size_t)(kb * 2 + 0) * 512);
            const short8v bl = *(const short8v*)(bb + (size_t)(kb * 2 + 1) * 512);
            acc = __builtin_amdgcn_mfma_f32_16x16x32_bf16(ah[kb], bh, acc, 0, 0, 0);
            acc = __builtin_amdgcn_mfma_f32_16x16x32_bf16(ah[kb], bl, acc, 0, 0, 0);
            acc = __builtin_amdgcn_mfma_f32_16x16x32_bf16(al[kb], bh, acc, 0, 0, 0);
        }
        const int colb = (nt & 7) * 16 + (lane & 15);
        const int row0 = mtile * 16 + (lane >> 4) * 4;
        if (nt < 8) {
#pragma unroll
            for (int r = 0; r < 4; ++r)
                xlh[(size_t)(row0 + r) * 128 + colb] = __float2half(acc[r] * XSCALE);
        } else {
#pragma unroll
            for (int r = 0; r < 4; ++r)
                xr[(size_t)(row0 + r) * 128 + colb] = acc[r];
        }
    }
}

// ---- layer 3 fused: blocks [0,MTILES) = frag-consume xl transform (2 waves);
// blocks [MTILES, MTILES+BATCH/8) = xr for pert rows (scalar, from fp32 xbuf).
__global__ __launch_bounds__(128)
void l3_fused_kernel(const short* __restrict__ xfrag, const float* __restrict__ x,
                     const short* __restrict__ wpk, __half* __restrict__ xlh,
                     const int* __restrict__ pert, const float* __restrict__ Wr3,
                     float* __restrict__ xr)
{
    if (blockIdx.x < MTILES) {
        const int mtile = blockIdx.x;
        const int wid   = threadIdx.x >> 6;
        const int lane  = threadIdx.x & 63;

        short8v ah[4], al[4];
        const short* ab = xfrag + ((size_t)mtile * 4 * 2) * 512 + lane * 8;
#pragma unroll
        for (int kb = 0; kb < 4; ++kb) {
            ah[kb] = *(const short8v*)(ab + (size_t)(kb * 2 + 0) * 512);
            al[kb] = *(const short8v*)(ab + (size_t)(kb * 2 + 1) * 512);
        }
#pragma unroll
        for (int i = 0; i < 4; ++i) {
            const int nt = wid * 4 + i;       // 0..7: xl tiles only
            const short* bb = wpk + ((size_t)nt * 4 * 2) * 512 + lane * 8;
            f32x4 acc = {0.f, 0.f, 0.f, 0.f};
#pragma unroll
            for (int kb = 0; kb < 4; ++kb) {
                const short8v bh = *(const short8v*)(bb + (size_t)(kb * 2 + 0) * 512);
                const short8v bl = *(const short8v*)(bb + (size_t)(kb * 2 + 1) * 512);
                acc = __builtin_amdgcn_mfma_f32_16x16x32_bf16(ah[kb], bh, acc, 0, 0, 0);
                acc = __builtin_amdgcn_mfma_f32_16x16x32_bf16(ah[kb], bl, acc, 0, 0, 0);
                acc = __builtin_amdgcn_mfma_f32_16x16x32_bf16(al[kb], bh, acc, 0, 0, 0);
            }
            const int colb = (nt & 7) * 16 + (lane & 15);
            const int row0 = mtile * 16 + (lane >> 4) * 4;
#pragma unroll
            for (int r = 0; r < 4; ++r)
                xlh[(size_t)(row0 + r) * 128 + colb] = __float2half(acc[r] * XSCALE);
        }
    } else {
        constexpr int G = 8;
        constexpr int K = 128;
        const int t  = threadIdx.x;
        const int i0 = (blockIdx.x - MTILES) * G;

        const float* __restrict__ xrow[G];
#pragma unroll
        for (int g = 0; g < G; ++g)
            xrow[g] = x + (size_t)pert[i0 + g] * K;

        float acc[G];
#pragma unroll
        for (int g = 0; g < G; ++g) acc[g] = 0.f;

        float4 xA[G], xB[G];
        float wA[4], wB[4];

        auto loadc = [&](float4* xv, float* w, int k) {
#pragma unroll
            for (int g = 0; g < G; ++g)
                xv[g] = *(const float4*)(xrow[g] + k);
#pragma unroll
            for (int u = 0; u < 4; ++u) w[u] = Wr3[(k + u) * 128 + t];
        };
        auto fmac = [&](const float4* xv, const float* w) {
#pragma unroll
            for (int g = 0; g < G; ++g) {
                acc[g] = fmaf(xv[g].x, w[0], acc[g]);
                acc[g] = fmaf(xv[g].y, w[1], acc[g]);
                acc[g] = fmaf(xv[g].z, w[2], acc[g]);
                acc[g] = fmaf(xv[g].w, w[3], acc[g]);
            }
        };

        loadc(xA, wA, 0);
        for (int k0 = 0; k0 < K; k0 += 8) {
            if (k0 + 4 < K) loadc(xB, wB, k0 + 4);
            fmac(xA, wA);
            if (k0 + 8 < K) loadc(xA, wA, k0 + 8);
            fmac(xB, wB);
        }
#pragma unroll
        for (int g = 0; g < G; ++g)
            xr[(size_t)(i0 + g) * 128 + t] = acc[g];
    }
}

// ---- CSR build: count degrees
__global__ __launch_bounds__(256)
void count_deg_kernel(const int* __restrict__ dst, int* __restrict__ deg, int E)
{
    const int e = blockIdx.x * blockDim.x + threadIdx.x;
    if (e < E) atomicAdd(&deg[dst[e]], 1);
}

// ---- exclusive scan over 20000 degrees; one block, LDS-staged coalesced I/O.
#define CHUNK 20
#define SCAN_PAD (1024 * CHUNK)
__global__ __launch_bounds__(1024)
void scan_kernel(const int* __restrict__ deg, int* __restrict__ off,
                 int* __restrict__ cursor)
{
    __shared__ int xs[SCAN_PAD];
    __shared__ int sums[1024];
    const int t = threadIdx.x;
    for (int i = t; i < SCAN_PAD; i += 1024)
        xs[i] = (i < N_NODES) ? deg[i] : 0;
    __syncthreads();

    const int base = t * CHUNK;
    int local[CHUNK];
    int s = 0;
#pragma unroll
    for (int i = 0; i < CHUNK; ++i) {
        local[i] = s;
        s += xs[base + i];
    }
    sums[t] = s;
    __syncthreads();
    for (int d = 1; d < 1024; d <<= 1) {
        int v = (t >= d) ? sums[t - d] : 0;
        __syncthreads();
        sums[t] += v;
        __syncthreads();
    }
    const int prev = (t == 0) ? 0 : sums[t - 1];
#pragma unroll
    for (int i = 0; i < CHUNK; ++i)
        xs[base + i] = prev + local[i];
    __syncthreads();
    for (int i = t; i < N_NODES; i += 1024) {
        const int o = xs[i];
        off[i] = o;
        cursor[i] = o;
    }
    if (t == 1023) off[N_NODES] = sums[1023];
}

// ---- scatter edges into dst-sorted order
__global__ __launch_bounds__(256)
void scatter_kernel(const int* __restrict__ src, const int* __restrict__ dst,
                    const float* __restrict__ ew, int* __restrict__ cursor,
                    int* __restrict__ ssrc, float* __restrict__ sew, int E)
{
    const int e = blockIdx.x * blockDim.x + threadIdx.x;
    if (e >= E) return;
    const int p = atomicAdd(&cursor[dst[e]], 1);
    ssrc[p] = src[e];
    sew[p]  = ew[e];
}

// ---- fused GATv2 layer. MODE 0: write next layer's A-fragments (bf16 hi/lo)
// directly from the epilogue (lane (h,j) holds exactly one fragment group:
// kb=cb>>5, kslot=j&3, fl=(node&15)+16*kslot). MODE 1: fragments + fp32 xbuf
// (layer 2; pert-row path needs fp32 rows). MODE 2: last layer -> d_out.
// Packed-fp16 score path + defer-max softmax as round 18.
template<int MODE>
__global__ __launch_bounds__(256)
void gat_node_kernel(const __half* __restrict__ xl, const float* __restrict__ xr,
                     const int* __restrict__ off, const int* __restrict__ ssrc,
                     const float* __restrict__ sew, const float* __restrict__ a,
                     const float* __restrict__ b, float* __restrict__ xout,
                     short* __restrict__ xfrag,
                     const int* __restrict__ nodemap, int nnodes)
{
    const int widx = (int)((blockIdx.x * blockDim.x + threadIdx.x) >> 6);
    if (widx >= nnodes) return;
    const int node = (MODE == 2) ? nodemap[widx] : widx;
    const int xrrow = widx;          // == node for MODE<2; batch row for MODE 2
    const int lane = threadIdx.x & 63;
    const int q  = lane >> 4;        // edge slot (4)
    const int h  = (lane >> 3) & 1;  // head
    const int j  = lane & 7;
    const int cb = h * 64 + j * 8;   // this lane's 8 dims

    const float* xrp = xr + (size_t)xrrow * 128 + cb;
    const h2v r01 = mk_h2(xrp[0] * XSCALE, xrp[1] * XSCALE);
    const h2v r23 = mk_h2(xrp[2] * XSCALE, xrp[3] * XSCALE);
    const h2v r45 = mk_h2(xrp[4] * XSCALE, xrp[5] * XSCALE);
    const h2v r67 = mk_h2(xrp[6] * XSCALE, xrp[7] * XSCALE);
    const h2v a01 = mk_h2(a[cb],     a[cb + 1]);
    const h2v a23 = mk_h2(a[cb + 2], a[cb + 3]);
    const h2v a45 = mk_h2(a[cb + 4], a[cb + 5]);
    const h2v a67 = mk_h2(a[cb + 6], a[cb + 7]);

    const int e0 = off[node], e1 = off[node + 1];
    const int nr = (e1 - e0 + 3) >> 2;   // rounds

    float m = -1e30f, s = 0.f;
    float4 accA = {0,0,0,0}, accB = {0,0,0,0};

    auto lde = [&](int r, float& w, bool& valid, uint4& raw) {
        const int ei  = e0 + r * 4 + q;
        valid = ei < e1;
        const int eic = valid ? ei : (e1 - 1);
        const int sn  = ssrc[eic];
        w = valid ? sew[eic] : 0.f;
        raw = *(const uint4*)(xl + (size_t)sn * 128 + cb);
    };
    auto plrelu = [](h2v v) {
        return __builtin_elementwise_max(v, v * (_Float16)0.2f);
    };

    float w_c; bool v_c; uint4 raw_c;
    if (nr > 0) lde(0, w_c, v_c, raw_c);

    for (int r = 0; r < nr; ++r) {
        float w_n; bool v_n; uint4 raw_n;
        if (r + 1 < nr) lde(r + 1, w_n, v_n, raw_n);   // issue-early

        const h2v x01 = __builtin_bit_cast(h2v, raw_c.x);
        const h2v x23 = __builtin_bit_cast(h2v, raw_c.y);
        const h2v x45 = __builtin_bit_cast(h2v, raw_c.z);
        const h2v x67 = __builtin_bit_cast(h2v, raw_c.w);

        const h2v v01 = plrelu(x01 + r01);
        const h2v v23 = plrelu(x23 + r23);
        const h2v v45 = plrelu(x45 + r45);
        const h2v v67 = plrelu(x67 + r67);
        float p = fdot2h(v01, a01, 0.f);
        p = fdot2h(v23, a23, p);
        p = fdot2h(v45, a45, p);
        p = fdot2h(v67, a67, p);
        p += __shfl_xor(p, 1, 64);
        p += __shfl_xor(p, 2, 64);
        p += __shfl_xor(p, 4, 64);       // per-8-lane group: own head's score
        p = v_c ? p * XINV : -1e30f;     // exact unscale (lrelu pos-homogeneous)

        const float f0x = (float)x01[0], f0y = (float)x01[1];
        const float f1x = (float)x23[0], f1y = (float)x23[1];
        const float f2x = (float)x45[0], f2y = (float)x45[1];
        const float f3x = (float)x67[0], f3y = (float)x67[1];

        const float d = p - m;           // group-uniform
        if (__any(d > 8.f)) {
            const float t   = __expf(-fabsf(d));
            const bool  pos = d > 0.f;
            const float rr  = pos ? t : 1.f;
            const float ex  = pos ? 1.f : t;
            m = pos ? p : m;
            const float c = ex * w_c;
            s = s * rr + ex;
            accA.x = fmaf(c, f0x, accA.x * rr); accA.y = fmaf(c, f0y, accA.y * rr);
            accA.z = fmaf(c, f1x, accA.z * rr); accA.w = fmaf(c, f1y, accA.w * rr);
            accB.x = fmaf(c, f2x, accB.x * rr); accB.y = fmaf(c, f2y, accB.y * rr);
            accB.z = fmaf(c, f3x, accB.z * rr); accB.w = fmaf(c, f3y, accB.w * rr);
        } else {
            const float ex = __expf(d);
            const float c  = ex * w_c;
            s += ex;
            accA.x = fmaf(c, f0x, accA.x); accA.y = fmaf(c, f0y, accA.y);
            accA.z = fmaf(c, f1x, accA.z); accA.w = fmaf(c, f1y, accA.w);
            accB.x = fmaf(c, f2x, accB.x); accB.y = fmaf(c, f2y, accB.y);
            accB.z = fmaf(c, f3x, accB.z); accB.w = fmaf(c, f3y, accB.w);
        }

        w_c = w_n; v_c = v_n; raw_c = raw_n;
    }

    // ---- merge the 4 slot states (across q: lane strides 16, 32)
    float mg = fmaxf(m, __shfl_xor(m, 16, 64));
    mg = fmaxf(mg, __shfl_xor(mg, 32, 64));
    const float rq = __expf(m - mg);     // 0 for dead slots
    float sq = s * rq;
    sq += __shfl_xor(sq, 16, 64);
    sq += __shfl_xor(sq, 32, 64);
    auto redsum2 = [](float v) {
        v += __shfl_xor(v, 16, 64);
        return v + __shfl_xor(v, 32, 64);
    };
    accA.x = redsum2(accA.x * rq); accA.y = redsum2(accA.y * rq);
    accA.z = redsum2(accA.z * rq); accA.w = redsum2(accA.w * rq);
    accB.x = redsum2(accB.x * rq); accB.y = redsum2(accB.y * rq);
    accB.z = redsum2(accB.z * rq); accB.w = redsum2(accB.w * rq);
    const float inv = XINV / (sq + 1e-16f);   // undo message scaling

    if (MODE < 2) {
        if (q == 0) {
            const float4 bA = *(const float4*)(b + cb);
            const float4 bB = *(const float4*)(b + cb + 4);
            float ov[8];
            ov[0] = accA.x * inv + bA.x; ov[0] = ov[0] > 0.f ? ov[0] : expm1f(ov[0]);
            ov[1] = accA.y * inv + bA.y; ov[1] = ov[1] > 0.f ? ov[1] : expm1f(ov[1]);
            ov[2] = accA.z * inv + bA.z; ov[2] = ov[2] > 0.f ? ov[2] : expm1f(ov[2]);
            ov[3] = accA.w * inv + bA.w; ov[3] = ov[3] > 0.f ? ov[3] : expm1f(ov[3]);
            ov[4] = accB.x * inv + bB.x; ov[4] = ov[4] > 0.f ? ov[4] : expm1f(ov[4]);
            ov[5] = accB.y * inv + bB.y; ov[5] = ov[5] > 0.f ? ov[5] : expm1f(ov[5]);
            ov[6] = accB.z * inv + bB.z; ov[6] = ov[6] > 0.f ? ov[6] : expm1f(ov[6]);
            ov[7] = accB.w * inv + bB.w; ov[7] = ov[7] > 0.f ? ov[7] : expm1f(ov[7]);

            // write next layer's A-fragment (bf16 hi/lo) directly
            const int mtile = node >> 4;
            const int kb    = cb >> 5;        // h*2 + (j>>2)
            const int fl    = (node & 15) + ((j & 3) << 4);
            short8v hi8, lo8;
#pragma unroll
            for (int e = 0; e < 8; ++e) {
                short hh, ll; bf16split(ov[e], hh, ll);
                hi8[e] = hh; lo8[e] = ll;
            }
            short* fb = xfrag + ((size_t)(mtile * 4 + kb) * 2) * 512 + fl * 8;
            *(short8v*)fb         = hi8;
            *(short8v*)(fb + 512) = lo8;

            if (MODE == 1) {   // layer 2: also fp32 rows for the pert path
                float* op = xout + (size_t)node * 128;
                *(float4*)(op + cb)     = make_float4(ov[0], ov[1], ov[2], ov[3]);
                *(float4*)(op + cb + 4) = make_float4(ov[4], ov[5], ov[6], ov[7]);
            }
        }
    } else {
        // mean over heads: bring other head's normalized value via stride-8 shfl
        float oA[4] = {accA.x * inv, accA.y * inv, accA.z * inv, accA.w * inv};
        float oB[4] = {accB.x * inv, accB.y * inv, accB.z * inv, accB.w * inv};
        float pA[4], pB[4];
#pragma unroll
        for (int k = 0; k < 4; ++k) {
            pA[k] = __shfl_xor(oA[k], 8, 64);
            pB[k] = __shfl_xor(oB[k], 8, 64);
        }
        if (q == 0 && h == 0) {
            const float4 bA = *(const float4*)(b + j * 8);
            const float4 bB = *(const float4*)(b + j * 8 + 4);
            float* op = xout + (size_t)widx * 64 + j * 8;
            op[0] = 0.5f * (oA[0] + pA[0]) + bA.x;
            op[1] = 0.5f * (oA[1] + pA[1]) + bA.y;
            op[2] = 0.5f * (oA[2] + pA[2]) + bA.z;
            op[3] = 0.5f * (oA[3] + pA[3]) + bA.w;
            op[4] = 0.5f * (oB[0] + pB[0]) + bB.x;
            op[5] = 0.5f * (oB[1] + pB[1]) + bB.y;
            op[6] = 0.5f * (oB[2] + pB[2]) + bB.z;
            op[7] = 0.5f * (oB[3] + pB[3]) + bB.w;
        }
    }
}

extern "C" void kernel_launch(void* const* d_in, const int* in_sizes, int n_in,
                              void* d_out, int out_size, void* d_ws, size_t ws_size,
                              hipStream_t stream)
{
    const int*   pert = (const int*)d_in[0];
    const int*   eidx = (const int*)d_in[1];
    const float* ew   = (const float*)d_in[2];
    const float* emb  = (const float*)d_in[3];
    const float* Wl[4] = {(const float*)d_in[4],  (const float*)d_in[8],
                          (const float*)d_in[12], (const float*)d_in[16]};
    const float* Wr[4] = {(const float*)d_in[5],  (const float*)d_in[9],
                          (const float*)d_in[13], (const float*)d_in[17]};
    const float* av[4] = {(const float*)d_in[6],  (const float*)d_in[10],
                          (const float*)d_in[14], (const float*)d_in[18]};
    const float* bv[4] = {(const float*)d_in[7],  (const float*)d_in[11],
                          (const float*)d_in[15], (const float*)d_in[19]};

    const int N = N_NODES, E = N_EDGES;
    const int* srcp = eidx;
    const int* dstp = eidx + E;

    // workspace layout
    float*  ws   = (float*)d_ws;
    float*  xbuf = ws;                                // N*128 f (layer-2 fp32 out)
    __half* xlh  = (__half*)(xbuf + (size_t)N * 128); // N*128 h (fp16 * XSCALE)
    float*  xr   = (float*)(xlh + (size_t)N * 128);   // N*128 f
    short*  wpk  = (short*)(xr + (size_t)N * 128);    // 4 layers x 65536 shorts
    short*  xfrag= wpk + 4 * 65536;                   // MTILES*4*2*512 shorts
    int*    deg  = (int*)(xfrag + (size_t)MTILES * 4 * 2 * 512); // N
    int*    off  = deg + N;                           // N+1
    int*    cur  = off + N + 1;                       // N
    int*    ssrc = cur + N;                           // E
    float*  sew  = (float*)(ssrc + E);                // E

    // ---- prep (zero deg + pack all W) then CSR build
    prep_kernel<<<(N + 14336 + 255) / 256, 256, 0, stream>>>(
        deg, Wl[0], Wr[0], Wl[1], Wr[1], Wl[2], Wr[2], Wl[3], Wr[3], wpk);
    count_deg_kernel<<<(E + 255) / 256, 256, 0, stream>>>(dstp, deg, E);
    scan_kernel<<<1, 1024, 0, stream>>>(deg, off, cur);
    scatter_kernel<<<(E + 255) / 256, 256, 0, stream>>>(srcp, dstp, ew, cur,
                                                        ssrc, sew, E);

    // ---- layer 0 (K=64, stage from fp32 emb); gat writes A-fragments
    mfma_transform_kernel<2, 4><<<MTILES, 256, 0, stream>>>(emb, wpk, xlh, xr);
    gat_node_kernel<0><<<(N * 64 + 255) / 256, 256, 0, stream>>>(
        xlh, xr, off, ssrc, sew, av[0], bv[0], xbuf, xfrag, nullptr, N);

    // ---- layer 1: frag-consume transform; gat writes fragments
    mfma_transform_frag_kernel<<<MTILES, 256, 0, stream>>>(
        xfrag, wpk + 1 * 65536, xlh, xr);
    gat_node_kernel<0><<<(N * 64 + 255) / 256, 256, 0, stream>>>(
        xlh, xr, off, ssrc, sew, av[1], bv[1], xbuf, xfrag, nullptr, N);

    // ---- layer 2: frag-consume transform; gat writes fragments + fp32 xbuf
    mfma_transform_frag_kernel<<<MTILES, 256, 0, stream>>>(
        xfrag, wpk + 2 * 65536, xlh, xr);
    gat_node_kernel<1><<<(N * 64 + 255) / 256, 256, 0, stream>>>(
        xlh, xr, off, ssrc, sew, av[2], bv[2], xbuf, xfrag, nullptr, N);

    // ---- layer 3: fused {xl frag transform | xr pert rows from xbuf}, then gat
    l3_fused_kernel<<<MTILES + BATCH / 8, 128, 0, stream>>>(
        xfrag, xbuf, wpk + 3 * 65536, xlh, pert, Wr[3], xr);
    gat_node_kernel<2><<<(BATCH * 64 + 255) / 256, 256, 0, stream>>>(
        xlh, xr, off, ssrc, sew, av[3], bv[3], (float*)d_out, xfrag, pert, BATCH);
}

// Round 20
// 223.089 us; speedup vs baseline: 1.0294x; 1.0294x over previous
//
#include <hip/hip_runtime.h>
#include <hip/hip_fp16.h>
#include <math.h>

#define N_NODES 20000
#define N_EDGES 400000
#define BATCH   4096
#define MTILES  (N_NODES / 16)   // 1250
#define XSCALE  1024.0f
#define XINV    (1.0f / 1024.0f)

typedef __attribute__((ext_vector_type(8))) short short8v;
typedef __attribute__((ext_vector_type(4))) float f32x4;
typedef __attribute__((ext_vector_type(2))) _Float16 h2v;

// fp16 dot-pair with fp32 accumulate (v_dot2_f32_f16); fp32 fallback if absent
__device__ __forceinline__ float fdot2h(h2v a, h2v b, float c)
{
#if __has_builtin(__builtin_amdgcn_fdot2)
    return __builtin_amdgcn_fdot2(a, b, c, false);
#else
    return fmaf((float)a[0], (float)b[0], fmaf((float)a[1], (float)b[1], c));
#endif
}

__device__ __forceinline__ h2v mk_h2(float x, float y)
{
    h2v r; r[0] = (_Float16)x; r[1] = (_Float16)y; return r;
}

// ---- split fp32 into bf16 hi + bf16 lo (truncation; hi+lo ~ 16 mantissa bits)
__device__ __forceinline__ void bf16split(float v, short& h, short& l)
{
    unsigned u  = __float_as_uint(v);
    unsigned hu = u & 0xFFFF0000u;
    h = (short)(hu >> 16);
    const float lo = v - __uint_as_float(hu);
    l = (short)(__float_as_uint(lo) >> 16);
}

// ---- prep: zero deg (t < N_NODES) + pack ALL 4 layers' W into B-fragments
__global__ __launch_bounds__(256)
void prep_kernel(int* __restrict__ deg,
                 const float* __restrict__ Wl0, const float* __restrict__ Wr0,
                 const float* __restrict__ Wl1, const float* __restrict__ Wr1,
                 const float* __restrict__ Wl2, const float* __restrict__ Wr2,
                 const float* __restrict__ Wl3, const float* __restrict__ Wr3,
                 short* __restrict__ wpk)
{
    const int t = blockIdx.x * 256 + threadIdx.x;
    if (t < N_NODES) { deg[t] = 0; return; }
    const int tp = t - N_NODES;
    if (tp >= 14336) return;
    int layer, base, K;
    const float *Wl, *Wr;
    if (tp < 2048)       { layer = 0; base = 0;     K = 64;  Wl = Wl0; Wr = Wr0; }
    else if (tp < 6144)  { layer = 1; base = 2048;  K = 128; Wl = Wl1; Wr = Wr1; }
    else if (tp < 10240) { layer = 2; base = 6144;  K = 128; Wl = Wl2; Wr = Wr2; }
    else                 { layer = 3; base = 10240; K = 128; Wl = Wl3; Wr = Wr3; }
    const int KB   = K / 32;
    const int tt   = tp - base;
    const int lane = tt & 63;
    const int kb   = (tt >> 6) % KB;
    const int nt   = tt / (64 * KB);
    const float* W = (nt < 8) ? Wl : Wr;
    const int col  = (nt & 7) * 16 + (lane & 15);
    const int k0   = kb * 32 + (lane >> 4) * 8;
    short8v h, l;
#pragma unroll
    for (int e = 0; e < 8; ++e) {
        short hh, ll; bf16split(W[(size_t)(k0 + e) * 128 + col], hh, ll);
        h[e] = hh; l[e] = ll;
    }
    short* ob = wpk + (size_t)layer * 65536
                    + ((size_t)(nt * KB + kb) * 2) * 512 + lane * 8;
    *(short8v*)ob         = h;
    *(short8v*)(ob + 512) = l;
}

// ---- MFMA transform with fused x packing (LDS stage, bf16 hi/lo in-reg,
// bf16x3 compensation). xl written as fp16 * XSCALE; xr stays fp32.
template<int KB, int NWAVES>
__global__ __launch_bounds__(NWAVES * 64)
void mfma_transform_kernel(const float* __restrict__ x,
                           const short* __restrict__ wpk,
                           __half* __restrict__ xlh, float* __restrict__ xr)
{
    constexpr int K  = KB * 32;
    constexpr int KP = K + 4;
    __shared__ float xs[16 * KP];
    const int mtile = blockIdx.x;
    const int wid   = threadIdx.x >> 6;
    const int lane  = threadIdx.x & 63;

    {
        const float4* __restrict__ src = (const float4*)(x + (size_t)mtile * 16 * K);
        for (int idx = threadIdx.x; idx < 16 * K / 4; idx += NWAVES * 64) {
            const int row = idx / (K / 4), c4 = idx % (K / 4);
            *(float4*)(xs + row * KP + c4 * 4) = src[idx];
        }
    }
    __syncthreads();

    short8v ah[KB], al[KB];
    {
        const float* ab = xs + (lane & 15) * KP + (lane >> 4) * 8;
#pragma unroll
        for (int kb = 0; kb < KB; ++kb) {
            const float4 f0 = *(const float4*)(ab + kb * 32);
            const float4 f1 = *(const float4*)(ab + kb * 32 + 4);
            float tmp[8] = {f0.x, f0.y, f0.z, f0.w, f1.x, f1.y, f1.z, f1.w};
#pragma unroll
            for (int e = 0; e < 8; ++e) {
                short hh, ll; bf16split(tmp[e], hh, ll);
                ah[kb][e] = hh; al[kb][e] = ll;
            }
        }
    }

#pragma unroll
    for (int i = 0; i < 4; ++i) {
        const int nt = wid * 4 + i;
        const short* bb = wpk + ((size_t)nt * KB * 2) * 512 + lane * 8;
        f32x4 acc = {0.f, 0.f, 0.f, 0.f};
#pragma unroll
        for (int kb = 0; kb < KB; ++kb) {
            const short8v bh = *(const short8v*)(bb + (size_t)(kb * 2 + 0) * 512);
            const short8v bl = *(const short8v*)(bb + (size_t)(kb * 2 + 1) * 512);
            acc = __builtin_amdgcn_mfma_f32_16x16x32_bf16(ah[kb], bh, acc, 0, 0, 0);
            acc = __builtin_amdgcn_mfma_f32_16x16x32_bf16(ah[kb], bl, acc, 0, 0, 0);
            acc = __builtin_amdgcn_mfma_f32_16x16x32_bf16(al[kb], bh, acc, 0, 0, 0);
        }
        const int colb = (nt & 7) * 16 + (lane & 15);
        const int row0 = mtile * 16 + (lane >> 4) * 4;
        if (nt < 8) {
#pragma unroll
            for (int r = 0; r < 4; ++r)
                xlh[(size_t)(row0 + r) * 128 + colb] = __float2half(acc[r] * XSCALE);
        } else {
#pragma unroll
            for (int r = 0; r < 4; ++r)
                xr[(size_t)(row0 + r) * 128 + colb] = acc[r];
        }
    }
}

// ---- layer 3 fused: blocks [0,MTILES) = MFMA xl transform (2 waves, xl only);
// blocks [MTILES, MTILES+BATCH/8) = xr for pert rows (scalar pipelined).
__global__ __launch_bounds__(128)
void l3_fused_kernel(const float* __restrict__ x, const short* __restrict__ wpk,
                     __half* __restrict__ xlh,
                     const int* __restrict__ pert, const float* __restrict__ Wr3,
                     float* __restrict__ xr)
{
    constexpr int K  = 128;
    constexpr int KP = K + 4;
    __shared__ float xs[16 * KP];

    if (blockIdx.x < MTILES) {
        const int mtile = blockIdx.x;
        const int wid   = threadIdx.x >> 6;
        const int lane  = threadIdx.x & 63;
        {
            const float4* __restrict__ src = (const float4*)(x + (size_t)mtile * 16 * K);
            for (int idx = threadIdx.x; idx < 16 * K / 4; idx += 128) {
                const int row = idx / (K / 4), c4 = idx % (K / 4);
                *(float4*)(xs + row * KP + c4 * 4) = src[idx];
            }
        }
        __syncthreads();

        short8v ah[4], al[4];
        {
            const float* ab = xs + (lane & 15) * KP + (lane >> 4) * 8;
#pragma unroll
            for (int kb = 0; kb < 4; ++kb) {
                const float4 f0 = *(const float4*)(ab + kb * 32);
                const float4 f1 = *(const float4*)(ab + kb * 32 + 4);
                float tmp[8] = {f0.x, f0.y, f0.z, f0.w, f1.x, f1.y, f1.z, f1.w};
#pragma unroll
                for (int e = 0; e < 8; ++e) {
                    short hh, ll; bf16split(tmp[e], hh, ll);
                    ah[kb][e] = hh; al[kb][e] = ll;
                }
            }
        }
#pragma unroll
        for (int i = 0; i < 4; ++i) {
            const int nt = wid * 4 + i;       // 0..7: xl tiles only
            const short* bb = wpk + ((size_t)nt * 4 * 2) * 512 + lane * 8;
            f32x4 acc = {0.f, 0.f, 0.f, 0.f};
#pragma unroll
            for (int kb = 0; kb < 4; ++kb) {
                const short8v bh = *(const short8v*)(bb + (size_t)(kb * 2 + 0) * 512);
                const short8v bl = *(const short8v*)(bb + (size_t)(kb * 2 + 1) * 512);
                acc = __builtin_amdgcn_mfma_f32_16x16x32_bf16(ah[kb], bh, acc, 0, 0, 0);
                acc = __builtin_amdgcn_mfma_f32_16x16x32_bf16(ah[kb], bl, acc, 0, 0, 0);
                acc = __builtin_amdgcn_mfma_f32_16x16x32_bf16(al[kb], bh, acc, 0, 0, 0);
            }
            const int colb = (nt & 7) * 16 + (lane & 15);
            const int row0 = mtile * 16 + (lane >> 4) * 4;
#pragma unroll
            for (int r = 0; r < 4; ++r)
                xlh[(size_t)(row0 + r) * 128 + colb] = __float2half(acc[r] * XSCALE);
        }
    } else {
        constexpr int G = 8;
        const int t  = threadIdx.x;
        const int i0 = (blockIdx.x - MTILES) * G;

        const float* __restrict__ xrow[G];
#pragma unroll
        for (int g = 0; g < G; ++g)
            xrow[g] = x + (size_t)pert[i0 + g] * K;

        float acc[G];
#pragma unroll
        for (int g = 0; g < G; ++g) acc[g] = 0.f;

        float4 xA[G], xB[G];
        float wA[4], wB[4];

        auto loadc = [&](float4* xv, float* w, int k) {
#pragma unroll
            for (int g = 0; g < G; ++g)
                xv[g] = *(const float4*)(xrow[g] + k);
#pragma unroll
            for (int u = 0; u < 4; ++u) w[u] = Wr3[(k + u) * 128 + t];
        };
        auto fmac = [&](const float4* xv, const float* w) {
#pragma unroll
            for (int g = 0; g < G; ++g) {
                acc[g] = fmaf(xv[g].x, w[0], acc[g]);
                acc[g] = fmaf(xv[g].y, w[1], acc[g]);
                acc[g] = fmaf(xv[g].z, w[2], acc[g]);
                acc[g] = fmaf(xv[g].w, w[3], acc[g]);
            }
        };

        loadc(xA, wA, 0);
        for (int k0 = 0; k0 < K; k0 += 8) {
            if (k0 + 4 < K) loadc(xB, wB, k0 + 4);
            fmac(xA, wA);
            if (k0 + 8 < K) loadc(xA, wA, k0 + 8);
            fmac(xB, wB);
        }
#pragma unroll
        for (int g = 0; g < G; ++g)
            xr[(size_t)(i0 + g) * 128 + t] = acc[g];
    }
}

// ---- CSR build: count degrees
__global__ __launch_bounds__(256)
void count_deg_kernel(const int* __restrict__ dst, int* __restrict__ deg, int E)
{
    const int e = blockIdx.x * blockDim.x + threadIdx.x;
    if (e < E) atomicAdd(&deg[dst[e]], 1);
}

// ---- exclusive scan over 20000 degrees; one block, LDS-staged coalesced I/O.
#define CHUNK 20
#define SCAN_PAD (1024 * CHUNK)
__global__ __launch_bounds__(1024)
void scan_kernel(const int* __restrict__ deg, int* __restrict__ off,
                 int* __restrict__ cursor)
{
    __shared__ int xs[SCAN_PAD];
    __shared__ int sums[1024];
    const int t = threadIdx.x;
    for (int i = t; i < SCAN_PAD; i += 1024)
        xs[i] = (i < N_NODES) ? deg[i] : 0;
    __syncthreads();

    const int base = t * CHUNK;
    int local[CHUNK];
    int s = 0;
#pragma unroll
    for (int i = 0; i < CHUNK; ++i) {
        local[i] = s;
        s += xs[base + i];
    }
    sums[t] = s;
    __syncthreads();
    for (int d = 1; d < 1024; d <<= 1) {
        int v = (t >= d) ? sums[t - d] : 0;
        __syncthreads();
        sums[t] += v;
        __syncthreads();
    }
    const int prev = (t == 0) ? 0 : sums[t - 1];
#pragma unroll
    for (int i = 0; i < CHUNK; ++i)
        xs[base + i] = prev + local[i];
    __syncthreads();
    for (int i = t; i < N_NODES; i += 1024) {
        const int o = xs[i];
        off[i] = o;
        cursor[i] = o;
    }
    if (t == 1023) off[N_NODES] = sums[1023];
}

// ---- scatter edges into dst-sorted order
__global__ __launch_bounds__(256)
void scatter_kernel(const int* __restrict__ src, const int* __restrict__ dst,
                    const float* __restrict__ ew, int* __restrict__ cursor,
                    int* __restrict__ ssrc, float* __restrict__ sew, int E)
{
    const int e = blockIdx.x * blockDim.x + threadIdx.x;
    if (e >= E) return;
    const int p = atomicAdd(&cursor[dst[e]], 1);
    ssrc[p] = src[e];
    sew[p]  = ew[e];
}

// ---- fused GATv2 layer: one wave per dst node, 4 edge slots (lane =
// q*16 + h*8 + j). Packed-fp16 score path via ext-vector _Float16 arithmetic
// (v_pk_add/mul + __builtin_elementwise_max -> v_pk_max) and v_dot2_f32_f16.
// Defer-max online softmax (T13). Messages accumulate fp32 in scaled space.
template<int LAST>
__global__ __launch_bounds__(256)
void gat_node_kernel(const __half* __restrict__ xl, const float* __restrict__ xr,
                     const int* __restrict__ off, const int* __restrict__ ssrc,
                     const float* __restrict__ sew, const float* __restrict__ a,
                     const float* __restrict__ b, float* __restrict__ xout,
                     const int* __restrict__ nodemap, int nnodes)
{
    const int widx = (int)((blockIdx.x * blockDim.x + threadIdx.x) >> 6);
    if (widx >= nnodes) return;
    const int node = LAST ? nodemap[widx] : widx;
    const int xrrow = widx;          // == node for !LAST; batch row for LAST
    const int lane = threadIdx.x & 63;
    const int q  = lane >> 4;        // edge slot (4)
    const int h  = (lane >> 3) & 1;  // head
    const int j  = lane & 7;
    const int cb = h * 64 + j * 8;   // this lane's 8 dims

    // r (scaled) and a as fp16 pairs, converted once per wave
    const float* xrp = xr + (size_t)xrrow * 128 + cb;
    const h2v r01 = mk_h2(xrp[0] * XSCALE, xrp[1] * XSCALE);
    const h2v r23 = mk_h2(xrp[2] * XSCALE, xrp[3] * XSCALE);
    const h2v r45 = mk_h2(xrp[4] * XSCALE, xrp[5] * XSCALE);
    const h2v r67 = mk_h2(xrp[6] * XSCALE, xrp[7] * XSCALE);
    const h2v a01 = mk_h2(a[cb],     a[cb + 1]);
    const h2v a23 = mk_h2(a[cb + 2], a[cb + 3]);
    const h2v a45 = mk_h2(a[cb + 4], a[cb + 5]);
    const h2v a67 = mk_h2(a[cb + 6], a[cb + 7]);

    const int e0 = off[node], e1 = off[node + 1];
    const int nr = (e1 - e0 + 3) >> 2;   // rounds

    float m = -1e30f, s = 0.f;
    float4 accA = {0,0,0,0}, accB = {0,0,0,0};

    auto lde = [&](int r, float& w, bool& valid, uint4& raw) {
        const int ei  = e0 + r * 4 + q;
        valid = ei < e1;
        const int eic = valid ? ei : (e1 - 1);
        const int sn  = ssrc[eic];
        w = valid ? sew[eic] : 0.f;
        raw = *(const uint4*)(xl + (size_t)sn * 128 + cb);
    };
    auto plrelu = [](h2v v) {
        return __builtin_elementwise_max(v, v * (_Float16)0.2f);
    };

    float w_c; bool v_c; uint4 raw_c;
    if (nr > 0) lde(0, w_c, v_c, raw_c);

    for (int r = 0; r < nr; ++r) {
        float w_n; bool v_n; uint4 raw_n;
        if (r + 1 < nr) lde(r + 1, w_n, v_n, raw_n);   // issue-early

        const h2v x01 = __builtin_bit_cast(h2v, raw_c.x);
        const h2v x23 = __builtin_bit_cast(h2v, raw_c.y);
        const h2v x45 = __builtin_bit_cast(h2v, raw_c.z);
        const h2v x67 = __builtin_bit_cast(h2v, raw_c.w);

        // packed score path: v = lrelu(x + r), p = sum v*a (fp32 acc)
        const h2v v01 = plrelu(x01 + r01);
        const h2v v23 = plrelu(x23 + r23);
        const h2v v45 = plrelu(x45 + r45);
        const h2v v67 = plrelu(x67 + r67);
        float p = fdot2h(v01, a01, 0.f);
        p = fdot2h(v23, a23, p);
        p = fdot2h(v45, a45, p);
        p = fdot2h(v67, a67, p);
        p += __shfl_xor(p, 1, 64);
        p += __shfl_xor(p, 2, 64);
        p += __shfl_xor(p, 4, 64);       // per-8-lane group: own head's score
        p = v_c ? p * XINV : -1e30f;     // exact unscale (lrelu pos-homogeneous)

        // fp32 x for message accumulation
        const float f0x = (float)x01[0], f0y = (float)x01[1];
        const float f1x = (float)x23[0], f1y = (float)x23[1];
        const float f2x = (float)x45[0], f2y = (float)x45[1];
        const float f3x = (float)x67[0], f3y = (float)x67[1];

        const float d = p - m;           // group-uniform
        if (__any(d > 8.f)) {
            // slow path (rare): full online update with rescale
            const float t   = __expf(-fabsf(d));
            const bool  pos = d > 0.f;
            const float rr  = pos ? t : 1.f;
            const float ex  = pos ? 1.f : t;
            m = pos ? p : m;
            const float c = ex * w_c;
            s = s * rr + ex;
            accA.x = fmaf(c, f0x, accA.x * rr); accA.y = fmaf(c, f0y, accA.y * rr);
            accA.z = fmaf(c, f1x, accA.z * rr); accA.w = fmaf(c, f1y, accA.w * rr);
            accB.x = fmaf(c, f2x, accB.x * rr); accB.y = fmaf(c, f2y, accB.y * rr);
            accB.z = fmaf(c, f3x, accB.z * rr); accB.w = fmaf(c, f3y, accB.w * rr);
        } else {
            // fast path: d <= 8 for every group -> no rescale needed
            const float ex = __expf(d);
            const float c  = ex * w_c;
            s += ex;
            accA.x = fmaf(c, f0x, accA.x); accA.y = fmaf(c, f0y, accA.y);
            accA.z = fmaf(c, f1x, accA.z); accA.w = fmaf(c, f1y, accA.w);
            accB.x = fmaf(c, f2x, accB.x); accB.y = fmaf(c, f2y, accB.y);
            accB.z = fmaf(c, f3x, accB.z); accB.w = fmaf(c, f3y, accB.w);
        }

        w_c = w_n; v_c = v_n; raw_c = raw_n;
    }

    // ---- merge the 4 slot states (across q: lane strides 16, 32)
    float mg = fmaxf(m, __shfl_xor(m, 16, 64));
    mg = fmaxf(mg, __shfl_xor(mg, 32, 64));
    const float rq = __expf(m - mg);     // 0 for dead slots
    float sq = s * rq;
    sq += __shfl_xor(sq, 16, 64);
    sq += __shfl_xor(sq, 32, 64);
    auto redsum2 = [](float v) {
        v += __shfl_xor(v, 16, 64);
        return v + __shfl_xor(v, 32, 64);
    };
    accA.x = redsum2(accA.x * rq); accA.y = redsum2(accA.y * rq);
    accA.z = redsum2(accA.z * rq); accA.w = redsum2(accA.w * rq);
    accB.x = redsum2(accB.x * rq); accB.y = redsum2(accB.y * rq);
    accB.z = redsum2(accB.z * rq); accB.w = redsum2(accB.w * rq);
    const float inv = XINV / (sq + 1e-16f);   // undo message scaling

    if (!LAST) {
        if (q == 0) {
            const float4 bA = *(const float4*)(b + cb);
            const float4 bB = *(const float4*)(b + cb + 4);
            float4 oA, oB;
            oA.x = accA.x * inv + bA.x; oA.x = oA.x > 0.f ? oA.x : expm1f(oA.x);
            oA.y = accA.y * inv + bA.y; oA.y = oA.y > 0.f ? oA.y : expm1f(oA.y);
            oA.z = accA.z * inv + bA.z; oA.z = oA.z > 0.f ? oA.z : expm1f(oA.z);
            oA.w = accA.w * inv + bA.w; oA.w = oA.w > 0.f ? oA.w : expm1f(oA.w);
            oB.x = accB.x * inv + bB.x; oB.x = oB.x > 0.f ? oB.x : expm1f(oB.x);
            oB.y = accB.y * inv + bB.y; oB.y = oB.y > 0.f ? oB.y : expm1f(oB.y);
            oB.z = accB.z * inv + bB.z; oB.z = oB.z > 0.f ? oB.z : expm1f(oB.z);
            oB.w = accB.w * inv + bB.w; oB.w = oB.w > 0.f ? oB.w : expm1f(oB.w);
            float* op = xout + (size_t)node * 128;
            *(float4*)(op + cb)     = oA;
            *(float4*)(op + cb + 4) = oB;
        }
    } else {
        // mean over heads: bring other head's normalized value via stride-8 shfl
        float oA[4] = {accA.x * inv, accA.y * inv, accA.z * inv, accA.w * inv};
        float oB[4] = {accB.x * inv, accB.y * inv, accB.z * inv, accB.w * inv};
        float pA[4], pB[4];
#pragma unroll
        for (int k = 0; k < 4; ++k) {
            pA[k] = __shfl_xor(oA[k], 8, 64);
            pB[k] = __shfl_xor(oB[k], 8, 64);
        }
        if (q == 0 && h == 0) {
            const float4 bA = *(const float4*)(b + j * 8);
            const float4 bB = *(const float4*)(b + j * 8 + 4);
            float* op = xout + (size_t)widx * 64 + j * 8;
            op[0] = 0.5f * (oA[0] + pA[0]) + bA.x;
            op[1] = 0.5f * (oA[1] + pA[1]) + bA.y;
            op[2] = 0.5f * (oA[2] + pA[2]) + bA.z;
            op[3] = 0.5f * (oA[3] + pA[3]) + bA.w;
            op[4] = 0.5f * (oB[0] + pB[0]) + bB.x;
            op[5] = 0.5f * (oB[1] + pB[1]) + bB.y;
            op[6] = 0.5f * (oB[2] + pB[2]) + bB.z;
            op[7] = 0.5f * (oB[3] + pB[3]) + bB.w;
        }
    }
}

extern "C" void kernel_launch(void* const* d_in, const int* in_sizes, int n_in,
                              void* d_out, int out_size, void* d_ws, size_t ws_size,
                              hipStream_t stream)
{
    const int*   pert = (const int*)d_in[0];
    const int*   eidx = (const int*)d_in[1];
    const float* ew   = (const float*)d_in[2];
    const float* emb  = (const float*)d_in[3];
    const float* Wl[4] = {(const float*)d_in[4],  (const float*)d_in[8],
                          (const float*)d_in[12], (const float*)d_in[16]};
    const float* Wr[4] = {(const float*)d_in[5],  (const float*)d_in[9],
                          (const float*)d_in[13], (const float*)d_in[17]};
    const float* av[4] = {(const float*)d_in[6],  (const float*)d_in[10],
                          (const float*)d_in[14], (const float*)d_in[18]};
    const float* bv[4] = {(const float*)d_in[7],  (const float*)d_in[11],
                          (const float*)d_in[15], (const float*)d_in[19]};

    const int N = N_NODES, E = N_EDGES;
    const int* srcp = eidx;
    const int* dstp = eidx + E;

    // workspace layout
    float*  ws   = (float*)d_ws;
    float*  xbuf = ws;                                // N*128 f
    __half* xlh  = (__half*)(xbuf + (size_t)N * 128); // N*128 h (fp16 * XSCALE)
    float*  xr   = (float*)(xlh + (size_t)N * 128);   // N*128 f
    short*  wpk  = (short*)(xr + (size_t)N * 128);    // 4 layers x 65536 shorts
    int*    deg  = (int*)(wpk + 4 * 65536);           // N
    int*    off  = deg + N;                           // N+1
    int*    cur  = off + N + 1;                       // N
    int*    ssrc = cur + N;                           // E
    float*  sew  = (float*)(ssrc + E);                // E

    // ---- prep (zero deg + pack all W) then CSR build
    prep_kernel<<<(N + 14336 + 255) / 256, 256, 0, stream>>>(
        deg, Wl[0], Wr[0], Wl[1], Wr[1], Wl[2], Wr[2], Wl[3], Wr[3], wpk);
    count_deg_kernel<<<(E + 255) / 256, 256, 0, stream>>>(dstp, deg, E);
    scan_kernel<<<1, 1024, 0, stream>>>(deg, off, cur);
    scatter_kernel<<<(E + 255) / 256, 256, 0, stream>>>(srcp, dstp, ew, cur,
                                                        ssrc, sew, E);

    // ---- layer 0 (K=64)
    mfma_transform_kernel<2, 4><<<MTILES, 256, 0, stream>>>(emb, wpk, xlh, xr);
    gat_node_kernel<0><<<(N * 64 + 255) / 256, 256, 0, stream>>>(
        xlh, xr, off, ssrc, sew, av[0], bv[0], xbuf, nullptr, N);

    // ---- layers 1,2 (K=128)
    for (int layer = 1; layer < 3; ++layer) {
        mfma_transform_kernel<4, 4><<<MTILES, 256, 0, stream>>>(
            xbuf, wpk + layer * 65536, xlh, xr);
        gat_node_kernel<0><<<(N * 64 + 255) / 256, 256, 0, stream>>>(
            xlh, xr, off, ssrc, sew, av[layer], bv[layer], xbuf, nullptr, N);
    }

    // ---- layer 3: fused {xl MFMA transform | xr pert rows}, then gat
    l3_fused_kernel<<<MTILES + BATCH / 8, 128, 0, stream>>>(
        xbuf, wpk + 3 * 65536, xlh, pert, Wr[3], xr);
    gat_node_kernel<1><<<(BATCH * 64 + 255) / 256, 256, 0, stream>>>(
        xlh, xr, off, ssrc, sew, av[3], bv[3], (float*)d_out, pert, BATCH);
}